// Round 2
// baseline (199.862 us; speedup 1.0000x reference)
//
#include <hip/hip_runtime.h>

#define TILE 16
#define HSZ 256
#define WSZ 256
#define NFC 64
#define PLANE (HSZ * WSZ)

// ============================================================================
// Kernel 1: per-pixel 3x3 filter prediction (48->9 conv + bias + ReLU).
// One 16x16 tile per 256-thread block; 18x18x48 unshuffled guidance in LDS.
// Output: fbuf[b][y][x][12] (9 filters + 3 pad, float4-aligned).
// ============================================================================
__global__ __launch_bounds__(256, 2) void filter_conv(
    const float* __restrict__ i_t,
    const float* __restrict__ wbuf,
    const float* __restrict__ bias,
    float* __restrict__ fbuf)
{
    __shared__ __align__(16) float4 xs4[12 * 324];   // 62208 B

    const int tid = threadIdx.x;
    const int px = tid & 15;
    const int py = tid >> 4;
    const int X0 = blockIdx.x * TILE;
    const int Y0 = blockIdx.y * TILE;
    const int b  = blockIdx.z;

    // Stage: x-channel (c3*16 + fy*4 + fx) <-> slot t = c3*4+fy, float4 lane fx.
    const float* itb = i_t + (size_t)b * 3 * (PLANE * 16);
    for (int v = tid; v < 3888; v += 256) {
        int sp = v / 12;
        int t  = v - sp * 12;
        int c3 = t >> 2;
        int fy = t & 3;
        int ly = sp / 18;
        int lx = sp - ly * 18;
        int Y = Y0 - 1 + ly;
        int X = X0 - 1 + lx;
        float4 val = make_float4(0.f, 0.f, 0.f, 0.f);
        if (Y >= 0 && Y < HSZ && X >= 0 && X < WSZ)
            val = *(const float4*)(itb + ((size_t)c3 * 1024 + (4 * Y + fy)) * 1024 + 4 * X);
        xs4[t * 324 + sp] = val;
    }
    __syncthreads();

    float acc[9];
#pragma unroll
    for (int oc = 0; oc < 9; ++oc) acc[oc] = bias[oc];

#pragma unroll 2
    for (int ic4 = 0; ic4 < 12; ++ic4) {
        // 9 taps of this 4-channel slice into registers
        float4 v[9];
#pragma unroll
        for (int t = 0; t < 9; ++t) {
            int ky = t / 3, kx = t - 3 * ky;
            v[t] = xs4[ic4 * 324 + (py + ky) * 18 + (px + kx)];
        }
        const int chb = ((ic4 >> 2) << 4) + ((ic4 & 3) << 2);  // ic base = c3*16 + fy*4
#pragma unroll
        for (int j = 0; j < 4; ++j) {
            const float* wp = wbuf + (size_t)(chb + j) * 9;     // + oc*432 + kk
#pragma unroll
            for (int t = 0; t < 9; ++t) {
                const float vv = (j == 0) ? v[t].x : (j == 1) ? v[t].y : (j == 2) ? v[t].z : v[t].w;
#pragma unroll
                for (int oc = 0; oc < 9; ++oc)
                    acc[oc] = fmaf(vv, wp[(size_t)oc * 432 + t], acc[oc]);
            }
        }
    }

    float4* fb4 = (float4*)(fbuf + ((size_t)b * PLANE + (Y0 + py) * WSZ + X0 + px) * 12);
    fb4[0] = make_float4(fmaxf(acc[0], 0.f), fmaxf(acc[1], 0.f), fmaxf(acc[2], 0.f), fmaxf(acc[3], 0.f));
    fb4[1] = make_float4(fmaxf(acc[4], 0.f), fmaxf(acc[5], 0.f), fmaxf(acc[6], 0.f), fmaxf(acc[7], 0.f));
    fb4[2] = make_float4(fmaxf(acc[8], 0.f), 0.f, 0.f, 0.f);
}

// ============================================================================
// Kernel 2: apply per-pixel filter to h. One (16x16 tile, 16-channel group)
// per 256-thread block -> 2048 blocks, 25.9 KB LDS, ~6 blocks/CU.
// ============================================================================
__global__ __launch_bounds__(256) void dyn_apply(
    const float* __restrict__ hbuf,
    const float* __restrict__ fbuf,
    float* __restrict__ out)
{
    __shared__ __align__(16) float hs[324 * 20];   // sp-major, 20-word stride (16 ch + 4 pad)

    const int tid = threadIdx.x;
    const int px = tid & 15;
    const int py = tid >> 4;
    const int cg = blockIdx.x & 3;          // channel group (16 ch each)
    const int X0 = (blockIdx.x >> 2) * TILE;
    const int Y0 = blockIdx.y * TILE;
    const int b  = blockIdx.z;

    // per-pixel filter (9 taps out of the 12-padded record)
    const float4* fp = (const float4*)(fbuf + ((size_t)b * PLANE + (Y0 + py) * WSZ + X0 + px) * 12);
    float4 f0 = fp[0], f1 = fp[1], f2 = fp[2];
    float flt[9] = {f0.x, f0.y, f0.z, f0.w, f1.x, f1.y, f1.z, f1.w, f2.x};

    // stage 16 channels' 18x18 halo tile
    const float* hp = hbuf + ((size_t)b * NFC + cg * 16) * PLANE;
    for (int idx = tid; idx < 5184; idx += 256) {
        int c  = idx / 324;
        int sp = idx - c * 324;
        int ly = sp / 18;
        int lx = sp - ly * 18;
        int Y = Y0 - 1 + ly;
        int X = X0 - 1 + lx;
        float vv = 0.f;
        if (Y >= 0 && Y < HSZ && X >= 0 && X < WSZ)
            vv = hp[(size_t)c * PLANE + (size_t)Y * WSZ + X];
        hs[sp * 20 + c] = vv;
    }
    __syncthreads();

    float4 a0 = make_float4(0.f, 0.f, 0.f, 0.f);
    float4 a1 = a0, a2 = a0, a3 = a0;
#pragma unroll
    for (int ky = 0; ky < 3; ++ky) {
#pragma unroll
        for (int kx = 0; kx < 3; ++kx) {
            const float f = flt[ky * 3 + kx];
            const float4* v4 = (const float4*)&hs[((py + ky) * 18 + (px + kx)) * 20];
            float4 v;
            v = v4[0]; a0.x = fmaf(v.x, f, a0.x); a0.y = fmaf(v.y, f, a0.y); a0.z = fmaf(v.z, f, a0.z); a0.w = fmaf(v.w, f, a0.w);
            v = v4[1]; a1.x = fmaf(v.x, f, a1.x); a1.y = fmaf(v.y, f, a1.y); a1.z = fmaf(v.z, f, a1.z); a1.w = fmaf(v.w, f, a1.w);
            v = v4[2]; a2.x = fmaf(v.x, f, a2.x); a2.y = fmaf(v.y, f, a2.y); a2.z = fmaf(v.z, f, a2.z); a2.w = fmaf(v.w, f, a2.w);
            v = v4[3]; a3.x = fmaf(v.x, f, a3.x); a3.y = fmaf(v.y, f, a3.y); a3.z = fmaf(v.z, f, a3.z); a3.w = fmaf(v.w, f, a3.w);
        }
    }

    const size_t o = ((size_t)b * NFC + cg * 16) * PLANE + (size_t)(Y0 + py) * WSZ + X0 + px;
    out[o]              = a0.x;  out[o + PLANE]      = a0.y;  out[o + 2 * (size_t)PLANE]  = a0.z;  out[o + 3 * (size_t)PLANE]  = a0.w;
    out[o + 4 * (size_t)PLANE]  = a1.x;  out[o + 5 * (size_t)PLANE]  = a1.y;  out[o + 6 * (size_t)PLANE]  = a1.z;  out[o + 7 * (size_t)PLANE]  = a1.w;
    out[o + 8 * (size_t)PLANE]  = a2.x;  out[o + 9 * (size_t)PLANE]  = a2.y;  out[o + 10 * (size_t)PLANE] = a2.z;  out[o + 11 * (size_t)PLANE] = a2.w;
    out[o + 12 * (size_t)PLANE] = a3.x;  out[o + 13 * (size_t)PLANE] = a3.y;  out[o + 14 * (size_t)PLANE] = a3.z;  out[o + 15 * (size_t)PLANE] = a3.w;
}

// ============================================================================
// Fallback: round-1 fused kernel (used only if ws_size is too small).
// ============================================================================
__global__ __launch_bounds__(256, 2) void fused_dynfilter(
    const float* __restrict__ hbuf,
    const float* __restrict__ i_t,
    const float* __restrict__ wbuf,
    const float* __restrict__ bias,
    float* __restrict__ out)
{
    __shared__ __align__(16) float smem[15552];
    float4* xs4 = (float4*)smem;

    const int tid = threadIdx.x;
    const int px = tid & 15;
    const int py = tid >> 4;
    const int X0 = blockIdx.x * TILE;
    const int Y0 = blockIdx.y * TILE;
    const int b  = blockIdx.z;

    const float* itb = i_t + (size_t)b * 3 * 1024 * 1024;
    for (int v = tid; v < 3888; v += 256) {
        int sp = v / 12;
        int t  = v - sp * 12;
        int c3 = t >> 2;
        int fy = t & 3;
        int ly = sp / 18;
        int lx = sp - ly * 18;
        int Y = Y0 - 1 + ly;
        int X = X0 - 1 + lx;
        float4 val = make_float4(0.f, 0.f, 0.f, 0.f);
        if (Y >= 0 && Y < HSZ && X >= 0 && X < WSZ)
            val = *(const float4*)(itb + ((size_t)c3 * 1024 + (4 * Y + fy)) * 1024 + 4 * X);
        xs4[t * 324 + sp] = val;
    }
    __syncthreads();

    float acc[9];
#pragma unroll
    for (int oc = 0; oc < 9; ++oc) acc[oc] = bias[oc];

#pragma unroll 1
    for (int ky = 0; ky < 3; ++ky) {
#pragma unroll 1
        for (int kx = 0; kx < 3; ++kx) {
            const int sp = (py + ky) * 18 + (px + kx);
            const int kk = ky * 3 + kx;
#pragma unroll
            for (int ic4 = 0; ic4 < 12; ++ic4) {
                float4 v = xs4[ic4 * 324 + sp];
                const int chb = ((ic4 >> 2) << 4) + ((ic4 & 3) << 2);
                const float* wp = wbuf + (size_t)chb * 9 + kk;
                const float vv[4] = {v.x, v.y, v.z, v.w};
#pragma unroll
                for (int j = 0; j < 4; ++j)
#pragma unroll
                    for (int oc = 0; oc < 9; ++oc)
                        acc[oc] = fmaf(vv[j], wp[j * 9 + (size_t)oc * 432], acc[oc]);
            }
        }
    }

    float flt[9];
#pragma unroll
    for (int oc = 0; oc < 9; ++oc) flt[oc] = fmaxf(acc[oc], 0.f);

    float4* hs4 = (float4*)smem;
#pragma unroll 1
    for (int cg = 0; cg < 16; ++cg) {
        __syncthreads();
        const float* hp = hbuf + ((size_t)b * NFC + cg * 4) * PLANE;
        for (int idx = tid; idx < 1296; idx += 256) {
            int c  = idx / 324;
            int sp = idx - c * 324;
            int ly = sp / 18;
            int lx = sp - ly * 18;
            int Y = Y0 - 1 + ly;
            int X = X0 - 1 + lx;
            float vv = 0.f;
            if (Y >= 0 && Y < HSZ && X >= 0 && X < WSZ)
                vv = hp[(size_t)c * PLANE + (size_t)Y * WSZ + X];
            smem[sp * 4 + c] = vv;
        }
        __syncthreads();

        float s0 = 0.f, s1 = 0.f, s2 = 0.f, s3 = 0.f;
#pragma unroll
        for (int ky = 0; ky < 3; ++ky)
#pragma unroll
            for (int kx = 0; kx < 3; ++kx) {
                float4 v = hs4[(py + ky) * 18 + (px + kx)];
                float f = flt[ky * 3 + kx];
                s0 = fmaf(v.x, f, s0);
                s1 = fmaf(v.y, f, s1);
                s2 = fmaf(v.z, f, s2);
                s3 = fmaf(v.w, f, s3);
            }
        size_t o = (((size_t)b * NFC + cg * 4) * HSZ + (Y0 + py)) * WSZ + (X0 + px);
        out[o]                         = s0;
        out[o + (size_t)PLANE]         = s1;
        out[o + (size_t)2 * PLANE]     = s2;
        out[o + (size_t)3 * PLANE]     = s3;
    }
}

extern "C" void kernel_launch(void* const* d_in, const int* in_sizes, int n_in,
                              void* d_out, int out_size, void* d_ws, size_t ws_size,
                              hipStream_t stream) {
    const float* h      = (const float*)d_in[0];
    const float* i_t    = (const float*)d_in[1];
    const float* conv_w = (const float*)d_in[2];
    const float* conv_b = (const float*)d_in[3];
    float* out = (float*)d_out;

    const int B = in_sizes[0] / (NFC * PLANE);
    const size_t ws_needed = (size_t)B * PLANE * 12 * sizeof(float);

    if (ws_size >= ws_needed) {
        float* fbuf = (float*)d_ws;
        dim3 g1(WSZ / TILE, HSZ / TILE, B);
        filter_conv<<<g1, 256, 0, stream>>>(i_t, conv_w, conv_b, fbuf);
        dim3 g2((WSZ / TILE) * 4, HSZ / TILE, B);
        dyn_apply<<<g2, 256, 0, stream>>>(h, fbuf, out);
    } else {
        dim3 grid(WSZ / TILE, HSZ / TILE, B);
        fused_dynfilter<<<grid, 256, 0, stream>>>(h, i_t, conv_w, conv_b, out);
    }
}

// Round 3
// 155.259 us; speedup vs baseline: 1.2873x; 1.2873x over previous
//
#include <hip/hip_runtime.h>

#define TILE 16
#define HSZ 256
#define WSZ 256
#define NFC 64
#define PLANE (HSZ * WSZ)

typedef __attribute__((ext_vector_type(8))) short short8;
typedef __attribute__((ext_vector_type(4))) float f32x4;

__device__ inline unsigned short f2bf(float f) {
    unsigned u = __builtin_bit_cast(unsigned, f);
    return (unsigned short)((u + 0x7fffu + ((u >> 16) & 1u)) >> 16);   // RTNE
}

// ============================================================================
// Kernel 1: filter prediction as MFMA implicit GEMM.
// C[pix, oc] = sum_k A[pix, k] * W[k, oc],  K = 432 (pad 448), N = 9 (pad 16).
// K order: k = tap*48 + ic  (48 % 8 == 0 -> every 8-k run = 8 contiguous
// channels at one tap -> one ds_read_b128 per A-fragment).
// LDS x-tile: bf16 [sp = 18x18][ch, stride 56] (36.3 KB), weights overlaid
// during prologue. One 16x16 px tile per block; wave w owns rows 4w..4w+3.
// ============================================================================
__global__ void filter_conv_mfma(const float* __restrict__ i_t,
                                 const float* __restrict__ wbuf,
                                 const float* __restrict__ bias,
                                 float* __restrict__ fbuf)
{
    __shared__ __align__(16) unsigned short xs[324 * 56];   // 36288 B

    const int tid = threadIdx.x;
    const int X0 = blockIdx.x * TILE;
    const int Y0 = blockIdx.y * TILE;
    const int b  = blockIdx.z;
    const int l15 = tid & 15;          // = oc for B/C layout, = px for A layout
    const int kg  = (tid >> 4) & 3;    // lane k-subgroup
    const int wv  = tid >> 6;          // wave -> rows 4*wv .. 4*wv+3

    // ---- phase 0: weights -> LDS (coalesced), build B-fragments in registers
    float* wsh = (float*)xs;           // overlay (15552 B < 36288 B)
    for (int i = tid; i < 3888; i += 256) wsh[i] = wbuf[i];
    __syncthreads();

    short8 wfrag[14];
#pragma unroll
    for (int kb = 0; kb < 14; ++kb) {
#pragma unroll
        for (int j = 0; j < 8; ++j) {
            const int k = kb * 32 + kg * 8 + j;
            float w = 0.f;
            if (k < 432 && l15 < 9) {
                const int kk = k / 48;           // tap 0..8
                const int ic = k - kk * 48;      // channel 0..47
                w = wsh[l15 * 432 + ic * 9 + kk];
            }
            wfrag[kb][j] = (short)f2bf(w);
        }
    }
    const float bv = (l15 < 9) ? bias[l15] : 0.f;
    __syncthreads();

    // ---- phase 1: stage unshuffled guidance tile as bf16 [sp][ch]
    const float* itb = i_t + (size_t)b * 3 * (PLANE * 16);
    for (int v = tid; v < 3888; v += 256) {
        const int sp = v / 12;
        const int t  = v - sp * 12;        // t = c3*4 + fy;  ch base = t*4
        const int c3 = t >> 2, fy = t & 3;
        const int ly = sp / 18, lx = sp - ly * 18;
        const int Y = Y0 - 1 + ly, X = X0 - 1 + lx;
        float4 val = make_float4(0.f, 0.f, 0.f, 0.f);
        if (Y >= 0 && Y < HSZ && X >= 0 && X < WSZ)
            val = *(const float4*)(itb + ((size_t)c3 * 1024 + (4 * Y + fy)) * 1024 + 4 * X);
        ushort4 u;
        u.x = f2bf(val.x); u.y = f2bf(val.y); u.z = f2bf(val.z); u.w = f2bf(val.w);
        *(ushort4*)(xs + sp * 56 + t * 4) = u;
    }
    __syncthreads();

    // ---- phase 2: 14 K-blocks x 4 row-tiles of MFMA
    f32x4 acc0 = {0.f, 0.f, 0.f, 0.f}, acc1 = acc0, acc2 = acc0, acc3 = acc0;
#pragma unroll
    for (int kb = 0; kb < 14; ++kb) {
        const int k0 = kb * 32 + kg * 8;
        int off = 0;
        if (k0 < 432) {
            const int kk  = k0 / 48;
            const int ic0 = k0 - kk * 48;
            const int ky  = kk / 3;
            const int kx  = kk - 3 * ky;
            off = ((wv * 4 + ky) * 18 + l15 + kx) * 56 + ic0;   // 16B-aligned
        }
        short8 a0 = *(const short8*)(xs + off);
        short8 a1 = *(const short8*)(xs + off + 1008);   // +1 row of pixels (18*56)
        short8 a2 = *(const short8*)(xs + off + 2016);
        short8 a3 = *(const short8*)(xs + off + 3024);
        acc0 = __builtin_amdgcn_mfma_f32_16x16x32_bf16(a0, wfrag[kb], acc0, 0, 0, 0);
        acc1 = __builtin_amdgcn_mfma_f32_16x16x32_bf16(a1, wfrag[kb], acc1, 0, 0, 0);
        acc2 = __builtin_amdgcn_mfma_f32_16x16x32_bf16(a2, wfrag[kb], acc2, 0, 0, 0);
        acc3 = __builtin_amdgcn_mfma_f32_16x16x32_bf16(a3, wfrag[kb], acc3, 0, 0, 0);
    }

    // ---- epilogue: C col = lane&15 = oc, row = kg*4 + r = px
    if (l15 < 9) {
        float* fb = fbuf + (size_t)b * PLANE * 12;
#pragma unroll
        for (int i = 0; i < 4; ++i) {
            const int py = wv * 4 + i;
            f32x4 A = (i == 0) ? acc0 : (i == 1) ? acc1 : (i == 2) ? acc2 : acc3;
#pragma unroll
            for (int r = 0; r < 4; ++r) {
                const int px = kg * 4 + r;
                fb[((size_t)(Y0 + py) * WSZ + X0 + px) * 12 + l15] = fmaxf(A[r] + bv, 0.f);
            }
        }
    }
}

// ============================================================================
// Kernel 2: apply per-pixel filters to h.
// Block = 16x16 px x 16 ch; thread = 4 px (x-quad) x 4 ch (stride-4).
// LDS: channel-plane layout hs[16][368] (row stride 20) -> conflict-free
// staging stores, 16B-aligned b128 window reads with uniform bank-quad spread.
// ============================================================================
__global__ void dyn_apply2(const float* __restrict__ hbuf,
                           const float* __restrict__ fbuf,
                           float* __restrict__ out)
{
    __shared__ __align__(16) float hs[16 * 368];   // 23552 B

    const int tid  = threadIdx.x;
    const int c_lo = tid & 3;
    const int pxq  = (tid >> 2) & 3;
    const int py   = tid >> 4;
    const int cg = blockIdx.x & 3;
    const int X0 = (blockIdx.x >> 2) * TILE;
    const int Y0 = blockIdx.y * TILE;
    const int b  = blockIdx.z;

    // per-pixel filters for this thread's 4 pixels (fbuf is L1/L2-hot)
    float flt[4][9];
    {
        const float* fb = fbuf + ((size_t)b * PLANE + (size_t)(Y0 + py) * WSZ + X0 + pxq * 4) * 12;
#pragma unroll
        for (int j = 0; j < 4; ++j) {
            float4 f0 = *(const float4*)(fb + j * 12);
            float4 f1 = *(const float4*)(fb + j * 12 + 4);
            float4 f2 = *(const float4*)(fb + j * 12 + 8);
            flt[j][0] = f0.x; flt[j][1] = f0.y; flt[j][2] = f0.z; flt[j][3] = f0.w;
            flt[j][4] = f1.x; flt[j][5] = f1.y; flt[j][6] = f1.z; flt[j][7] = f1.w;
            flt[j][8] = f2.x;
        }
    }

    // stage 16 channel planes (18 rows x 18 cols, row stride 20)
    const float* hp = hbuf + ((size_t)b * NFC + cg * 16) * PLANE;
    for (int idx = tid; idx < 5184; idx += 256) {
        const int c  = idx / 324;
        const int r  = idx - c * 324;
        const int ly = r / 18, lx = r - ly * 18;
        const int Y = Y0 - 1 + ly, X = X0 - 1 + lx;
        float v = 0.f;
        if (Y >= 0 && Y < HSZ && X >= 0 && X < WSZ)
            v = hp[(size_t)c * PLANE + (size_t)Y * WSZ + X];
        hs[c * 368 + ly * 20 + lx] = v;
    }
    __syncthreads();

    float a[4][4];
#pragma unroll
    for (int cc = 0; cc < 4; ++cc)
#pragma unroll
        for (int j = 0; j < 4; ++j) a[cc][j] = 0.f;

#pragma unroll
    for (int cc = 0; cc < 4; ++cc) {
        const float* pl = hs + (c_lo + 4 * cc) * 368;
#pragma unroll
        for (int ky = 0; ky < 3; ++ky) {
            const float* rp = pl + (py + ky) * 20 + pxq * 4;
            float4 w0 = *(const float4*)rp;        // cols 4pxq .. 4pxq+3
            float2 w1 = *(const float2*)(rp + 4);  // cols 4pxq+4, +5
            const float vs[6] = {w0.x, w0.y, w0.z, w0.w, w1.x, w1.y};
#pragma unroll
            for (int kx = 0; kx < 3; ++kx)
#pragma unroll
                for (int j = 0; j < 4; ++j)
                    a[cc][j] = fmaf(vs[kx + j], flt[j][ky * 3 + kx], a[cc][j]);
        }
    }

#pragma unroll
    for (int cc = 0; cc < 4; ++cc) {
        const int ch = cg * 16 + c_lo + 4 * cc;
        float4 o4 = make_float4(a[cc][0], a[cc][1], a[cc][2], a[cc][3]);
        *(float4*)(out + ((size_t)b * NFC + ch) * PLANE
                       + (size_t)(Y0 + py) * WSZ + X0 + pxq * 4) = o4;
    }
}

// ============================================================================
// Fallback (ws too small): round-1 fused kernel.
// ============================================================================
__global__ __launch_bounds__(256, 2) void fused_dynfilter(
    const float* __restrict__ hbuf,
    const float* __restrict__ i_t,
    const float* __restrict__ wbuf,
    const float* __restrict__ bias,
    float* __restrict__ out)
{
    __shared__ __align__(16) float smem[15552];
    float4* xs4 = (float4*)smem;

    const int tid = threadIdx.x;
    const int px = tid & 15;
    const int py = tid >> 4;
    const int X0 = blockIdx.x * TILE;
    const int Y0 = blockIdx.y * TILE;
    const int b  = blockIdx.z;

    const float* itb = i_t + (size_t)b * 3 * 1024 * 1024;
    for (int v = tid; v < 3888; v += 256) {
        int sp = v / 12;
        int t  = v - sp * 12;
        int c3 = t >> 2, fy = t & 3;
        int ly = sp / 18, lx = sp - ly * 18;
        int Y = Y0 - 1 + ly, X = X0 - 1 + lx;
        float4 val = make_float4(0.f, 0.f, 0.f, 0.f);
        if (Y >= 0 && Y < HSZ && X >= 0 && X < WSZ)
            val = *(const float4*)(itb + ((size_t)c3 * 1024 + (4 * Y + fy)) * 1024 + 4 * X);
        xs4[t * 324 + sp] = val;
    }
    __syncthreads();

    float acc[9];
#pragma unroll
    for (int oc = 0; oc < 9; ++oc) acc[oc] = bias[oc];

#pragma unroll 1
    for (int ky = 0; ky < 3; ++ky)
#pragma unroll 1
        for (int kx = 0; kx < 3; ++kx) {
            const int sp = (py + ky) * 18 + (px + kx);
            const int kk = ky * 3 + kx;
#pragma unroll
            for (int ic4 = 0; ic4 < 12; ++ic4) {
                float4 v = xs4[ic4 * 324 + sp];
                const int chb = ((ic4 >> 2) << 4) + ((ic4 & 3) << 2);
                const float* wp = wbuf + (size_t)chb * 9 + kk;
                const float vv[4] = {v.x, v.y, v.z, v.w};
#pragma unroll
                for (int j = 0; j < 4; ++j)
#pragma unroll
                    for (int oc = 0; oc < 9; ++oc)
                        acc[oc] = fmaf(vv[j], wp[j * 9 + (size_t)oc * 432], acc[oc]);
            }
        }

    float flt[9];
#pragma unroll
    for (int oc = 0; oc < 9; ++oc) flt[oc] = fmaxf(acc[oc], 0.f);

    float4* hs4 = (float4*)smem;
#pragma unroll 1
    for (int cg = 0; cg < 16; ++cg) {
        __syncthreads();
        const float* hp = hbuf + ((size_t)b * NFC + cg * 4) * PLANE;
        for (int idx = tid; idx < 1296; idx += 256) {
            int c  = idx / 324;
            int sp = idx - c * 324;
            int ly = sp / 18, lx = sp - ly * 18;
            int Y = Y0 - 1 + ly, X = X0 - 1 + lx;
            float vv = 0.f;
            if (Y >= 0 && Y < HSZ && X >= 0 && X < WSZ)
                vv = hp[(size_t)c * PLANE + (size_t)Y * WSZ + X];
            smem[sp * 4 + c] = vv;
        }
        __syncthreads();

        float s0 = 0.f, s1 = 0.f, s2 = 0.f, s3 = 0.f;
#pragma unroll
        for (int ky = 0; ky < 3; ++ky)
#pragma unroll
            for (int kx = 0; kx < 3; ++kx) {
                float4 v = hs4[(py + ky) * 18 + (px + kx)];
                float f = flt[ky * 3 + kx];
                s0 = fmaf(v.x, f, s0);
                s1 = fmaf(v.y, f, s1);
                s2 = fmaf(v.z, f, s2);
                s3 = fmaf(v.w, f, s3);
            }
        size_t o = (((size_t)b * NFC + cg * 4) * HSZ + (Y0 + py)) * WSZ + (X0 + px);
        out[o]                     = s0;
        out[o + (size_t)PLANE]     = s1;
        out[o + (size_t)2 * PLANE] = s2;
        out[o + (size_t)3 * PLANE] = s3;
    }
}

extern "C" void kernel_launch(void* const* d_in, const int* in_sizes, int n_in,
                              void* d_out, int out_size, void* d_ws, size_t ws_size,
                              hipStream_t stream) {
    const float* h      = (const float*)d_in[0];
    const float* i_t    = (const float*)d_in[1];
    const float* conv_w = (const float*)d_in[2];
    const float* conv_b = (const float*)d_in[3];
    float* out = (float*)d_out;

    const int B = in_sizes[0] / (NFC * PLANE);
    const size_t ws_needed = (size_t)B * PLANE * 12 * sizeof(float);

    if (ws_size >= ws_needed) {
        float* fbuf = (float*)d_ws;
        dim3 g1(WSZ / TILE, HSZ / TILE, B);
        filter_conv_mfma<<<g1, 256, 0, stream>>>(i_t, conv_w, conv_b, fbuf);
        dim3 g2((WSZ / TILE) * 4, HSZ / TILE, B);
        dyn_apply2<<<g2, 256, 0, stream>>>(h, fbuf, out);
    } else {
        dim3 grid(WSZ / TILE, HSZ / TILE, B);
        fused_dynfilter<<<grid, 256, 0, stream>>>(h, i_t, conv_w, conv_b, out);
    }
}

// Round 4
// 138.704 us; speedup vs baseline: 1.4409x; 1.1194x over previous
//
#include <hip/hip_runtime.h>

#define TILE 16
#define HSZ 256
#define WSZ 256
#define NFC 64
#define PLANE (HSZ * WSZ)

typedef __attribute__((ext_vector_type(8))) short short8;
typedef __attribute__((ext_vector_type(4))) float f32x4;

__device__ inline unsigned short f2bf(float f) {
    unsigned u = __builtin_bit_cast(unsigned, f);
    return (unsigned short)((u + 0x7fffu + ((u >> 16) & 1u)) >> 16);   // RTNE
}

// ============================================================================
// Kernel 0 (run once per launch): repack conv_w into the MFMA B-fragment
// layout wfragG[kb][lane][8] bf16, kb=0..13 (K=432 padded to 448), so every
// filter_conv block loads fragments with 14 coalesced dwordx4 reads (L2-hot)
// instead of rebuilding them (~600 VALU + 112 LDS reads per thread).
// ============================================================================
__global__ void prep_wfrag(const float* __restrict__ wbuf,
                           unsigned short* __restrict__ wfragG)
{
    const int kb   = blockIdx.x;        // 0..13
    const int lane = threadIdx.x;       // 0..63
    const int l15  = lane & 15;         // oc
    const int kg   = lane >> 4;
    unsigned short v8[8];
#pragma unroll
    for (int j = 0; j < 8; ++j) {
        const int k = kb * 32 + kg * 8 + j;    // k = tap*48 + ic
        float w = 0.f;
        if (k < 432 && l15 < 9) {
            const int kk = k / 48;             // tap 0..8
            const int ic = k - kk * 48;        // channel 0..47
            w = wbuf[l15 * 432 + ic * 9 + kk];
        }
        v8[j] = f2bf(w);
    }
    unsigned short* p = wfragG + (size_t)kb * 512 + lane * 8;
    *(ushort4*)(p)     = ushort4{v8[0], v8[1], v8[2], v8[3]};
    *(ushort4*)(p + 4) = ushort4{v8[4], v8[5], v8[6], v8[7]};
}

// ============================================================================
// Kernel 1: filter prediction as MFMA implicit GEMM.
// Tile 16(x) x 8(y) px, 128 threads (2 waves), 1024 blocks.
// LDS: xs[sp = 10x18][48 ch] bf16, stride 48 (16B-aligned A-frags since every
// 8-k run of the tap-major K order is 8 contiguous channels at one tap).
// Epilogue transposes C through LDS -> coalesced float4 stores.
// ============================================================================
__global__ __launch_bounds__(128) void filter_conv_mfma2(
    const float* __restrict__ i_t,
    const unsigned short* __restrict__ wfragG,
    const float* __restrict__ bias,
    float* __restrict__ fbuf)
{
    __shared__ __align__(16) unsigned short xs[180 * 48];   // 17280 B

    const int tid  = threadIdx.x;
    const int X0 = blockIdx.x * 16;
    const int Y0 = blockIdx.y * 8;
    const int b  = blockIdx.z;
    const int lane = tid & 63;
    const int l15  = tid & 15;          // A: px col / B,C: oc
    const int kg   = (tid >> 4) & 3;    // k-subgroup
    const int wv   = tid >> 6;          // wave -> rows 4wv..4wv+3

    const float bv = (l15 < 9) ? bias[l15] : 0.f;
    const float* itb = i_t + (size_t)b * 3 * (PLANE * 16);

    // ---- stage guidance tile (10x18 sp x 12 float4-slots = 2160 jobs), batched
    {
        ushort4 sreg[9]; int sdst[9];
#pragma unroll
        for (int k = 0; k < 9; ++k) {
            const int v = tid + 128 * k;
            const int sp = v / 12, t = v - sp * 12;     // t = c3*4+fy, ch base t*4
            const int c3 = t >> 2, fy = t & 3;
            const int ly = sp / 18, lx = sp - ly * 18;
            const int Y = Y0 - 1 + ly, X = X0 - 1 + lx;
            float4 val = make_float4(0.f, 0.f, 0.f, 0.f);
            if ((unsigned)Y < HSZ && (unsigned)X < WSZ)
                val = *(const float4*)(itb + ((size_t)c3 * 1024 + (4 * Y + fy)) * 1024 + 4 * X);
            sreg[k] = ushort4{f2bf(val.x), f2bf(val.y), f2bf(val.z), f2bf(val.w)};
            sdst[k] = sp * 48 + t * 4;
        }
#pragma unroll
        for (int k = 0; k < 9; ++k) *(ushort4*)(xs + sdst[k]) = sreg[k];
    }
    {
        ushort4 sreg[8]; int sdst[8];
#pragma unroll
        for (int k = 0; k < 8; ++k) {
            const int v = tid + 128 * (k + 9);
            const int sp = v / 12, t = v - sp * 12;
            const int c3 = t >> 2, fy = t & 3;
            const int ly = sp / 18, lx = sp - ly * 18;
            const int Y = Y0 - 1 + ly, X = X0 - 1 + lx;
            float4 val = make_float4(0.f, 0.f, 0.f, 0.f);
            if (v < 2160 && (unsigned)Y < HSZ && (unsigned)X < WSZ)
                val = *(const float4*)(itb + ((size_t)c3 * 1024 + (4 * Y + fy)) * 1024 + 4 * X);
            sreg[k] = ushort4{f2bf(val.x), f2bf(val.y), f2bf(val.z), f2bf(val.w)};
            sdst[k] = (v < 2160) ? (sp * 48 + t * 4) : -1;
        }
#pragma unroll
        for (int k = 0; k < 8; ++k)
            if (sdst[k] >= 0) *(ushort4*)(xs + sdst[k]) = sreg[k];
    }

    // ---- B-fragments: 14 coalesced dwordx4 from wfragG (L2-hot)
    short8 wf[14];
#pragma unroll
    for (int kb = 0; kb < 14; ++kb)
        wf[kb] = *(const short8*)(wfragG + (size_t)kb * 512 + lane * 8);

    __syncthreads();

    // ---- 14 K-blocks x 4 row-tiles of MFMA
    f32x4 acc0 = {0.f, 0.f, 0.f, 0.f}, acc1 = acc0, acc2 = acc0, acc3 = acc0;
#pragma unroll
    for (int kb = 0; kb < 14; ++kb) {
        const int k0 = kb * 32 + kg * 8;
        int off = 0;
        if (k0 < 432) {
            const int kk  = k0 / 48;
            const int ic0 = k0 - kk * 48;
            const int ky  = kk / 3;
            const int kx  = kk - 3 * ky;
            off = ((wv * 4 + ky) * 18 + l15 + kx) * 48 + ic0;   // 16B-aligned
        }
        short8 a0 = *(const short8*)(xs + off);
        short8 a1 = *(const short8*)(xs + off + 864);    // +1 px row (18*48)
        short8 a2 = *(const short8*)(xs + off + 1728);
        short8 a3 = *(const short8*)(xs + off + 2592);
        acc0 = __builtin_amdgcn_mfma_f32_16x16x32_bf16(a0, wf[kb], acc0, 0, 0, 0);
        acc1 = __builtin_amdgcn_mfma_f32_16x16x32_bf16(a1, wf[kb], acc1, 0, 0, 0);
        acc2 = __builtin_amdgcn_mfma_f32_16x16x32_bf16(a2, wf[kb], acc2, 0, 0, 0);
        acc3 = __builtin_amdgcn_mfma_f32_16x16x32_bf16(a3, wf[kb], acc3, 0, 0, 0);
    }

    // ---- epilogue: transpose through LDS -> coalesced float4 stores
    __syncthreads();
    float* lf = (float*)xs;                    // 8*16*12 = 1536 floats (6144 B)
    if (l15 < 9) {
#pragma unroll
        for (int i = 0; i < 4; ++i) {
            const int py = wv * 4 + i;
            f32x4 A = (i == 0) ? acc0 : (i == 1) ? acc1 : (i == 2) ? acc2 : acc3;
#pragma unroll
            for (int r = 0; r < 4; ++r) {
                const int px = kg * 4 + r;
                lf[(py * 16 + px) * 12 + l15] = fmaxf(A[r] + bv, 0.f);
            }
        }
    }
    __syncthreads();
    float* fb = fbuf + (size_t)b * PLANE * 12;
#pragma unroll
    for (int k = 0; k < 3; ++k) {
        const int v = tid + 128 * k;           // 384 float4 jobs
        const int row = v / 48, off = v - row * 48;
        *(float4*)(fb + ((size_t)(Y0 + row) * WSZ + X0) * 12 + off * 4) =
            *(const float4*)(lf + v * 4);
    }
}

// ============================================================================
// Kernel 2: apply per-pixel filters to h.
// Block = 16x16 px x 8 ch (4096 blocks); thread = 4 px x 2 ch.
// LDS: hs[8 ch][18 rows][24 cols] floats, 13824 B (~8 resident blocks/CU).
// Staging: fixed 4-round float4 batch (loads issued before any ds_write) ->
// ~4 KB outstanding per wave; every float4 is fully in- or out-of-bounds.
// ============================================================================
__global__ __launch_bounds__(256) void dyn_apply3(
    const float* __restrict__ hbuf,
    const float* __restrict__ fbuf,
    float* __restrict__ out)
{
    __shared__ __align__(16) float hs[8 * 432];   // 8 * 18*24 = 13824 B

    const int tid  = threadIdx.x;
    const int pxq  = tid & 3;
    const int py   = (tid >> 2) & 15;
    const int c_lo = tid >> 6;                    // 0..3 (uniform per wave)
    const int cg = blockIdx.x & 7;
    const int X0 = (blockIdx.x >> 3) * TILE;
    const int Y0 = blockIdx.y * TILE;
    const int b  = blockIdx.z;

    // per-pixel filters for this thread's 4 pixels (shared by 4 c_lo -> L1)
    float flt[4][9];
    {
        const float* fb = fbuf + ((size_t)b * PLANE + (size_t)(Y0 + py) * WSZ + X0 + pxq * 4) * 12;
#pragma unroll
        for (int j = 0; j < 4; ++j) {
            float4 f0 = *(const float4*)(fb + j * 12);
            float4 f1 = *(const float4*)(fb + j * 12 + 4);
            float  f8 = fb[j * 12 + 8];
            flt[j][0] = f0.x; flt[j][1] = f0.y; flt[j][2] = f0.z; flt[j][3] = f0.w;
            flt[j][4] = f1.x; flt[j][5] = f1.y; flt[j][6] = f1.z; flt[j][7] = f1.w;
            flt[j][8] = f8;
        }
    }

    // stage 8 channel planes: 864 float4 jobs, LDS destination linear in v
    const float* hp = hbuf + ((size_t)b * NFC + cg * 8) * PLANE;
    {
        float4 rv[4]; int vv[4];
#pragma unroll
        for (int k = 0; k < 4; ++k) {
            const int v = tid + 256 * k;
            vv[k] = v;
            const int c = v / 108, r = v - c * 108;
            const int row = r / 6, xf4 = r - row * 6;
            const int Y  = Y0 - 1 + row;
            const int X4 = X0 - 4 + xf4 * 4;
            float4 val = make_float4(0.f, 0.f, 0.f, 0.f);
            if (v < 864 && (unsigned)Y < HSZ && (unsigned)X4 < WSZ)
                val = *(const float4*)(hp + (size_t)c * PLANE + (size_t)Y * WSZ + X4);
            rv[k] = val;
        }
#pragma unroll
        for (int k = 0; k < 4; ++k)
            if (vv[k] < 864) *(float4*)(hs + vv[k] * 4) = rv[k];
    }
    __syncthreads();

    float a[2][4];
#pragma unroll
    for (int cc = 0; cc < 2; ++cc)
#pragma unroll
        for (int j = 0; j < 4; ++j) a[cc][j] = 0.f;

#pragma unroll
    for (int cc = 0; cc < 2; ++cc) {
        const float* pl = hs + (c_lo + 4 * cc) * 432;
#pragma unroll
        for (int ky = 0; ky < 3; ++ky) {
            const float* rp = pl + (py + ky) * 24 + pxq * 4;
            float4 w0 = *(const float4*)rp;          // cols 0..3  (use 3)
            float4 w1 = *(const float4*)(rp + 4);    // cols 4..7
            float  w8 = rp[8];                       // col 8
            const float vs[9] = {w0.x, w0.y, w0.z, w0.w, w1.x, w1.y, w1.z, w1.w, w8};
#pragma unroll
            for (int kx = 0; kx < 3; ++kx)
#pragma unroll
                for (int j = 0; j < 4; ++j)
                    a[cc][j] = fmaf(vs[3 + kx + j], flt[j][ky * 3 + kx], a[cc][j]);
        }
    }

#pragma unroll
    for (int cc = 0; cc < 2; ++cc) {
        const int ch = cg * 8 + c_lo + 4 * cc;
        *(float4*)(out + ((size_t)b * NFC + ch) * PLANE
                       + (size_t)(Y0 + py) * WSZ + X0 + pxq * 4)
            = make_float4(a[cc][0], a[cc][1], a[cc][2], a[cc][3]);
    }
}

// ============================================================================
// Mid fallback (ws fits fbuf only): round-3 filter kernel (proven).
// ============================================================================
__global__ void filter_conv_mfma(const float* __restrict__ i_t,
                                 const float* __restrict__ wbuf,
                                 const float* __restrict__ bias,
                                 float* __restrict__ fbuf)
{
    __shared__ __align__(16) unsigned short xs[324 * 56];

    const int tid = threadIdx.x;
    const int X0 = blockIdx.x * TILE;
    const int Y0 = blockIdx.y * TILE;
    const int b  = blockIdx.z;
    const int l15 = tid & 15;
    const int kg  = (tid >> 4) & 3;
    const int wv  = tid >> 6;

    float* wsh = (float*)xs;
    for (int i = tid; i < 3888; i += 256) wsh[i] = wbuf[i];
    __syncthreads();

    short8 wfrag[14];
#pragma unroll
    for (int kb = 0; kb < 14; ++kb) {
#pragma unroll
        for (int j = 0; j < 8; ++j) {
            const int k = kb * 32 + kg * 8 + j;
            float w = 0.f;
            if (k < 432 && l15 < 9) {
                const int kk = k / 48;
                const int ic = k - kk * 48;
                w = wsh[l15 * 432 + ic * 9 + kk];
            }
            wfrag[kb][j] = (short)f2bf(w);
        }
    }
    const float bv = (l15 < 9) ? bias[l15] : 0.f;
    __syncthreads();

    const float* itb = i_t + (size_t)b * 3 * (PLANE * 16);
    for (int v = tid; v < 3888; v += 256) {
        const int sp = v / 12;
        const int t  = v - sp * 12;
        const int c3 = t >> 2, fy = t & 3;
        const int ly = sp / 18, lx = sp - ly * 18;
        const int Y = Y0 - 1 + ly, X = X0 - 1 + lx;
        float4 val = make_float4(0.f, 0.f, 0.f, 0.f);
        if (Y >= 0 && Y < HSZ && X >= 0 && X < WSZ)
            val = *(const float4*)(itb + ((size_t)c3 * 1024 + (4 * Y + fy)) * 1024 + 4 * X);
        ushort4 u;
        u.x = f2bf(val.x); u.y = f2bf(val.y); u.z = f2bf(val.z); u.w = f2bf(val.w);
        *(ushort4*)(xs + sp * 56 + t * 4) = u;
    }
    __syncthreads();

    f32x4 acc0 = {0.f, 0.f, 0.f, 0.f}, acc1 = acc0, acc2 = acc0, acc3 = acc0;
#pragma unroll
    for (int kb = 0; kb < 14; ++kb) {
        const int k0 = kb * 32 + kg * 8;
        int off = 0;
        if (k0 < 432) {
            const int kk  = k0 / 48;
            const int ic0 = k0 - kk * 48;
            const int ky  = kk / 3;
            const int kx  = kk - 3 * ky;
            off = ((wv * 4 + ky) * 18 + l15 + kx) * 56 + ic0;
        }
        short8 a0 = *(const short8*)(xs + off);
        short8 a1 = *(const short8*)(xs + off + 1008);
        short8 a2 = *(const short8*)(xs + off + 2016);
        short8 a3 = *(const short8*)(xs + off + 3024);
        acc0 = __builtin_amdgcn_mfma_f32_16x16x32_bf16(a0, wfrag[kb], acc0, 0, 0, 0);
        acc1 = __builtin_amdgcn_mfma_f32_16x16x32_bf16(a1, wfrag[kb], acc1, 0, 0, 0);
        acc2 = __builtin_amdgcn_mfma_f32_16x16x32_bf16(a2, wfrag[kb], acc2, 0, 0, 0);
        acc3 = __builtin_amdgcn_mfma_f32_16x16x32_bf16(a3, wfrag[kb], acc3, 0, 0, 0);
    }

    if (l15 < 9) {
        float* fb = fbuf + (size_t)b * PLANE * 12;
#pragma unroll
        for (int i = 0; i < 4; ++i) {
            const int py = wv * 4 + i;
            f32x4 A = (i == 0) ? acc0 : (i == 1) ? acc1 : (i == 2) ? acc2 : acc3;
#pragma unroll
            for (int r = 0; r < 4; ++r) {
                const int px = kg * 4 + r;
                fb[((size_t)(Y0 + py) * WSZ + X0 + px) * 12 + l15] = fmaxf(A[r] + bv, 0.f);
            }
        }
    }
}

// ============================================================================
// Last-resort fallback (no usable ws): round-1 fused kernel.
// ============================================================================
__global__ __launch_bounds__(256, 2) void fused_dynfilter(
    const float* __restrict__ hbuf,
    const float* __restrict__ i_t,
    const float* __restrict__ wbuf,
    const float* __restrict__ bias,
    float* __restrict__ out)
{
    __shared__ __align__(16) float smem[15552];
    float4* xs4 = (float4*)smem;

    const int tid = threadIdx.x;
    const int px = tid & 15;
    const int py = tid >> 4;
    const int X0 = blockIdx.x * TILE;
    const int Y0 = blockIdx.y * TILE;
    const int b  = blockIdx.z;

    const float* itb = i_t + (size_t)b * 3 * 1024 * 1024;
    for (int v = tid; v < 3888; v += 256) {
        int sp = v / 12;
        int t  = v - sp * 12;
        int c3 = t >> 2, fy = t & 3;
        int ly = sp / 18, lx = sp - ly * 18;
        int Y = Y0 - 1 + ly, X = X0 - 1 + lx;
        float4 val = make_float4(0.f, 0.f, 0.f, 0.f);
        if (Y >= 0 && Y < HSZ && X >= 0 && X < WSZ)
            val = *(const float4*)(itb + ((size_t)c3 * 1024 + (4 * Y + fy)) * 1024 + 4 * X);
        xs4[t * 324 + sp] = val;
    }
    __syncthreads();

    float acc[9];
#pragma unroll
    for (int oc = 0; oc < 9; ++oc) acc[oc] = bias[oc];

#pragma unroll 1
    for (int ky = 0; ky < 3; ++ky)
#pragma unroll 1
        for (int kx = 0; kx < 3; ++kx) {
            const int sp = (py + ky) * 18 + (px + kx);
            const int kk = ky * 3 + kx;
#pragma unroll
            for (int ic4 = 0; ic4 < 12; ++ic4) {
                float4 v = xs4[ic4 * 324 + sp];
                const int chb = ((ic4 >> 2) << 4) + ((ic4 & 3) << 2);
                const float* wp = wbuf + (size_t)chb * 9 + kk;
                const float vv[4] = {v.x, v.y, v.z, v.w};
#pragma unroll
                for (int j = 0; j < 4; ++j)
#pragma unroll
                    for (int oc = 0; oc < 9; ++oc)
                        acc[oc] = fmaf(vv[j], wp[j * 9 + (size_t)oc * 432], acc[oc]);
            }
        }

    float flt[9];
#pragma unroll
    for (int oc = 0; oc < 9; ++oc) flt[oc] = fmaxf(acc[oc], 0.f);

    float4* hs4 = (float4*)smem;
#pragma unroll 1
    for (int cg = 0; cg < 16; ++cg) {
        __syncthreads();
        const float* hp = hbuf + ((size_t)b * NFC + cg * 4) * PLANE;
        for (int idx = tid; idx < 1296; idx += 256) {
            int c  = idx / 324;
            int sp = idx - c * 324;
            int ly = sp / 18, lx = sp - ly * 18;
            int Y = Y0 - 1 + ly, X = X0 - 1 + lx;
            float vv = 0.f;
            if (Y >= 0 && Y < HSZ && X >= 0 && X < WSZ)
                vv = hp[(size_t)c * PLANE + (size_t)Y * WSZ + X];
            smem[sp * 4 + c] = vv;
        }
        __syncthreads();

        float s0 = 0.f, s1 = 0.f, s2 = 0.f, s3 = 0.f;
#pragma unroll
        for (int ky = 0; ky < 3; ++ky)
#pragma unroll
            for (int kx = 0; kx < 3; ++kx) {
                float4 v = hs4[(py + ky) * 18 + (px + kx)];
                float f = flt[ky * 3 + kx];
                s0 = fmaf(v.x, f, s0);
                s1 = fmaf(v.y, f, s1);
                s2 = fmaf(v.z, f, s2);
                s3 = fmaf(v.w, f, s3);
            }
        size_t o = (((size_t)b * NFC + cg * 4) * HSZ + (Y0 + py)) * WSZ + (X0 + px);
        out[o]                     = s0;
        out[o + (size_t)PLANE]     = s1;
        out[o + (size_t)2 * PLANE] = s2;
        out[o + (size_t)3 * PLANE] = s3;
    }
}

extern "C" void kernel_launch(void* const* d_in, const int* in_sizes, int n_in,
                              void* d_out, int out_size, void* d_ws, size_t ws_size,
                              hipStream_t stream) {
    const float* h      = (const float*)d_in[0];
    const float* i_t    = (const float*)d_in[1];
    const float* conv_w = (const float*)d_in[2];
    const float* conv_b = (const float*)d_in[3];
    float* out = (float*)d_out;

    const int B = in_sizes[0] / (NFC * PLANE);
    const size_t fbuf_sz  = (size_t)B * PLANE * 12 * sizeof(float);
    const size_t wfrag_sz = 14 * 512 * sizeof(unsigned short);   // 14336 B

    if (ws_size >= fbuf_sz + wfrag_sz) {
        float* fbuf = (float*)d_ws;
        unsigned short* wfragG = (unsigned short*)((char*)d_ws + fbuf_sz);
        prep_wfrag<<<dim3(14), 64, 0, stream>>>(conv_w, wfragG);
        dim3 g1(WSZ / 16, HSZ / 8, B);
        filter_conv_mfma2<<<g1, 128, 0, stream>>>(i_t, wfragG, conv_b, fbuf);
        dim3 g2((WSZ / TILE) * 8, HSZ / TILE, B);
        dyn_apply3<<<g2, 256, 0, stream>>>(h, fbuf, out);
    } else if (ws_size >= fbuf_sz) {
        float* fbuf = (float*)d_ws;
        dim3 g1(WSZ / TILE, HSZ / TILE, B);
        filter_conv_mfma<<<g1, 256, 0, stream>>>(i_t, conv_w, conv_b, fbuf);
        dim3 g2((WSZ / TILE) * 8, HSZ / TILE, B);
        dyn_apply3<<<g2, 256, 0, stream>>>(h, fbuf, out);
    } else {
        dim3 grid(WSZ / TILE, HSZ / TILE, B);
        fused_dynfilter<<<grid, 256, 0, stream>>>(h, i_t, conv_w, conv_b, out);
    }
}

// Round 5
// 137.720 us; speedup vs baseline: 1.4512x; 1.0071x over previous
//
#include <hip/hip_runtime.h>

#define TILE 16
#define HSZ 256
#define WSZ 256
#define NFC 64
#define PLANE (HSZ * WSZ)

typedef __attribute__((ext_vector_type(8))) short short8;
typedef __attribute__((ext_vector_type(4))) float f32x4;

__device__ inline unsigned short f2bf(float f) {
    unsigned u = __builtin_bit_cast(unsigned, f);
    return (unsigned short)((u + 0x7fffu + ((u >> 16) & 1u)) >> 16);   // RTNE
}

// ============================================================================
// Kernel 0: repack conv_w into MFMA B-fragment layout wfragG[kb][lane][8] bf16.
// ============================================================================
__global__ void prep_wfrag(const float* __restrict__ wbuf,
                           unsigned short* __restrict__ wfragG)
{
    const int kb   = blockIdx.x;        // 0..13
    const int lane = threadIdx.x;       // 0..63
    const int l15  = lane & 15;         // oc
    const int kg   = lane >> 4;
    unsigned short v8[8];
#pragma unroll
    for (int j = 0; j < 8; ++j) {
        const int k = kb * 32 + kg * 8 + j;    // k = tap*48 + ic
        float w = 0.f;
        if (k < 432 && l15 < 9) {
            const int kk = k / 48;
            const int ic = k - kk * 48;
            w = wbuf[l15 * 432 + ic * 9 + kk];
        }
        v8[j] = f2bf(w);
    }
    unsigned short* p = wfragG + (size_t)kb * 512 + lane * 8;
    *(ushort4*)(p)     = ushort4{v8[0], v8[1], v8[2], v8[3]};
    *(ushort4*)(p + 4) = ushort4{v8[4], v8[5], v8[6], v8[7]};
}

// ============================================================================
// Kernel 1: filter prediction as MFMA implicit GEMM (tile 16x8 px, 128 thr).
// Single 17-round batched staging (all loads in flight before ds_writes).
// ============================================================================
__global__ __launch_bounds__(128) void filter_conv_mfma2(
    const float* __restrict__ i_t,
    const unsigned short* __restrict__ wfragG,
    const float* __restrict__ bias,
    float* __restrict__ fbuf)
{
    __shared__ __align__(16) unsigned short xs[180 * 48];   // 17280 B

    const int tid  = threadIdx.x;
    const int X0 = blockIdx.x * 16;
    const int Y0 = blockIdx.y * 8;
    const int b  = blockIdx.z;
    const int lane = tid & 63;
    const int l15  = tid & 15;
    const int kg   = (tid >> 4) & 3;
    const int wv   = tid >> 6;

    const float bv = (l15 < 9) ? bias[l15] : 0.f;
    const float* itb = i_t + (size_t)b * 3 * (PLANE * 16);

    // ---- stage guidance tile: 2160 float4 jobs in one 17-round batch
    {
        float4 lreg[17]; int sdst[17];
#pragma unroll
        for (int k = 0; k < 17; ++k) {
            const int v = tid + 128 * k;
            const int sp = v / 12, t = v - sp * 12;     // t = c3*4+fy
            const int c3 = t >> 2, fy = t & 3;
            const int ly = sp / 18, lx = sp - ly * 18;
            const int Y = Y0 - 1 + ly, X = X0 - 1 + lx;
            float4 val = make_float4(0.f, 0.f, 0.f, 0.f);
            if (v < 2160 && (unsigned)Y < HSZ && (unsigned)X < WSZ)
                val = *(const float4*)(itb + ((size_t)c3 * 1024 + (4 * Y + fy)) * 1024 + 4 * X);
            lreg[k] = val;
            sdst[k] = (v < 2160) ? (sp * 48 + t * 4) : -1;
        }
#pragma unroll
        for (int k = 0; k < 17; ++k) {
            if (sdst[k] >= 0) {
                ushort4 u{f2bf(lreg[k].x), f2bf(lreg[k].y), f2bf(lreg[k].z), f2bf(lreg[k].w)};
                *(ushort4*)(xs + sdst[k]) = u;
            }
        }
    }

    // ---- B-fragments: 14 coalesced dwordx4 from wfragG (L2-hot)
    short8 wf[14];
#pragma unroll
    for (int kb = 0; kb < 14; ++kb)
        wf[kb] = *(const short8*)(wfragG + (size_t)kb * 512 + lane * 8);

    __syncthreads();

    // ---- 14 K-blocks x 4 row-tiles of MFMA
    f32x4 acc0 = {0.f, 0.f, 0.f, 0.f}, acc1 = acc0, acc2 = acc0, acc3 = acc0;
#pragma unroll
    for (int kb = 0; kb < 14; ++kb) {
        const int k0 = kb * 32 + kg * 8;
        int off = 0;
        if (k0 < 432) {
            const int kk  = k0 / 48;
            const int ic0 = k0 - kk * 48;
            const int ky  = kk / 3;
            const int kx  = kk - 3 * ky;
            off = ((wv * 4 + ky) * 18 + l15 + kx) * 48 + ic0;   // 16B-aligned
        }
        short8 a0 = *(const short8*)(xs + off);
        short8 a1 = *(const short8*)(xs + off + 864);
        short8 a2 = *(const short8*)(xs + off + 1728);
        short8 a3 = *(const short8*)(xs + off + 2592);
        acc0 = __builtin_amdgcn_mfma_f32_16x16x32_bf16(a0, wf[kb], acc0, 0, 0, 0);
        acc1 = __builtin_amdgcn_mfma_f32_16x16x32_bf16(a1, wf[kb], acc1, 0, 0, 0);
        acc2 = __builtin_amdgcn_mfma_f32_16x16x32_bf16(a2, wf[kb], acc2, 0, 0, 0);
        acc3 = __builtin_amdgcn_mfma_f32_16x16x32_bf16(a3, wf[kb], acc3, 0, 0, 0);
    }

    // ---- epilogue: transpose through LDS -> coalesced float4 stores
    __syncthreads();
    float* lf = (float*)xs;
    if (l15 < 9) {
#pragma unroll
        for (int i = 0; i < 4; ++i) {
            const int py = wv * 4 + i;
            f32x4 A = (i == 0) ? acc0 : (i == 1) ? acc1 : (i == 2) ? acc2 : acc3;
#pragma unroll
            for (int r = 0; r < 4; ++r) {
                const int px = kg * 4 + r;
                lf[(py * 16 + px) * 12 + l15] = fmaxf(A[r] + bv, 0.f);
            }
        }
    }
    __syncthreads();
    float* fb = fbuf + (size_t)b * PLANE * 12;
#pragma unroll
    for (int k = 0; k < 3; ++k) {
        const int v = tid + 128 * k;           // 384 float4 jobs
        const int row = v / 48, off = v - row * 48;
        *(float4*)(fb + ((size_t)(Y0 + row) * WSZ + X0) * 12 + off * 4) =
            *(const float4*)(lf + v * 4);
    }
}

// ============================================================================
// Kernel 2: apply per-pixel filters to h.
// Block = 32x16 px x 8 ch (2048 blocks, 256 thr); thread = 4 px x 4 ch.
// LDS: hs[8 ch][18 rows][40 cols], data at cols 3..36 = h cols X0-1..X0+32
// (pad cols never read). Scalar batched staging: 34 cols/row -> halo fetch
// ratio 1.195x (vs 1.69x for the float4-24col scheme), loads all in flight
// before any ds_write. Window reads stay 16B-aligned b128.
// ============================================================================
__global__ __launch_bounds__(256, 4) void dyn_apply4(
    const float* __restrict__ hbuf,
    const float* __restrict__ fbuf,
    float* __restrict__ out)
{
    __shared__ __align__(16) float hs[8 * 18 * 40];   // 23040 B

    const int tid  = threadIdx.x;
    const int pq   = tid & 7;                 // px group of 4 (x = X0+pq*4..+3)
    const int py   = (tid >> 3) & 15;
    const int c_lo = tid >> 7;                // 0..1 (uniform per wave-pair)
    const int cg = blockIdx.x & 7;
    const int X0 = (blockIdx.x >> 3) * 32;
    const int Y0 = blockIdx.y * TILE;
    const int b  = blockIdx.z;

    // per-pixel filters for this thread's 4 pixels
    float flt[4][9];
    {
        const float* fb = fbuf + ((size_t)b * PLANE + (size_t)(Y0 + py) * WSZ + X0 + pq * 4) * 12;
#pragma unroll
        for (int j = 0; j < 4; ++j) {
            float4 f0 = *(const float4*)(fb + j * 12);
            float4 f1 = *(const float4*)(fb + j * 12 + 4);
            float  f8 = fb[j * 12 + 8];
            flt[j][0] = f0.x; flt[j][1] = f0.y; flt[j][2] = f0.z; flt[j][3] = f0.w;
            flt[j][4] = f1.x; flt[j][5] = f1.y; flt[j][6] = f1.z; flt[j][7] = f1.w;
            flt[j][8] = f8;
        }
    }

    // stage 8 channel planes: 8 * 18 * 34 = 4896 scalar jobs, 20 rounds
    const float* hp = hbuf + ((size_t)b * NFC + cg * 8) * PLANE;
    {
        float rv[20]; int dst[20];
#pragma unroll
        for (int k = 0; k < 20; ++k) {
            const int v = tid + 256 * k;
            const int c = v / 612;                   // 18*34
            const int r = v - c * 612;
            const int row = r / 34, l = r - row * 34;
            const int Y = Y0 - 1 + row;
            const int X = X0 - 1 + l;
            float val = 0.f;
            if (v < 4896 && (unsigned)Y < HSZ && (unsigned)X < WSZ)
                val = hp[(size_t)c * PLANE + (size_t)Y * WSZ + X];
            rv[k] = val;
            dst[k] = (v < 4896) ? (c * 720 + row * 40 + 3 + l) : -1;
        }
#pragma unroll
        for (int k = 0; k < 20; ++k)
            if (dst[k] >= 0) hs[dst[k]] = rv[k];
    }
    __syncthreads();

    float a[4][4];
#pragma unroll
    for (int cc = 0; cc < 4; ++cc)
#pragma unroll
        for (int j = 0; j < 4; ++j) a[cc][j] = 0.f;

#pragma unroll
    for (int cc = 0; cc < 4; ++cc) {
        const float* pl = hs + (c_lo + 2 * cc) * 720;
#pragma unroll
        for (int ky = 0; ky < 3; ++ky) {
            const float* rp = pl + (py + ky) * 40 + pq * 4;
            float4 w0 = *(const float4*)rp;          // LDS cols pq*4 .. +3
            float4 w1 = *(const float4*)(rp + 4);
            float  w8 = rp[8];
            const float vs[9] = {w0.x, w0.y, w0.z, w0.w, w1.x, w1.y, w1.z, w1.w, w8};
#pragma unroll
            for (int kx = 0; kx < 3; ++kx)
#pragma unroll
                for (int j = 0; j < 4; ++j)
                    a[cc][j] = fmaf(vs[3 + kx + j], flt[j][ky * 3 + kx], a[cc][j]);
        }
    }

#pragma unroll
    for (int cc = 0; cc < 4; ++cc) {
        const int ch = cg * 8 + c_lo + 2 * cc;
        *(float4*)(out + ((size_t)b * NFC + ch) * PLANE
                       + (size_t)(Y0 + py) * WSZ + X0 + pq * 4)
            = make_float4(a[cc][0], a[cc][1], a[cc][2], a[cc][3]);
    }
}

// ============================================================================
// Mid fallback (ws fits fbuf only): round-3 self-contained filter kernel.
// ============================================================================
__global__ void filter_conv_mfma(const float* __restrict__ i_t,
                                 const float* __restrict__ wbuf,
                                 const float* __restrict__ bias,
                                 float* __restrict__ fbuf)
{
    __shared__ __align__(16) unsigned short xs[324 * 56];

    const int tid = threadIdx.x;
    const int X0 = blockIdx.x * TILE;
    const int Y0 = blockIdx.y * TILE;
    const int b  = blockIdx.z;
    const int l15 = tid & 15;
    const int kg  = (tid >> 4) & 3;
    const int wv  = tid >> 6;

    float* wsh = (float*)xs;
    for (int i = tid; i < 3888; i += 256) wsh[i] = wbuf[i];
    __syncthreads();

    short8 wfrag[14];
#pragma unroll
    for (int kb = 0; kb < 14; ++kb) {
#pragma unroll
        for (int j = 0; j < 8; ++j) {
            const int k = kb * 32 + kg * 8 + j;
            float w = 0.f;
            if (k < 432 && l15 < 9) {
                const int kk = k / 48;
                const int ic = k - kk * 48;
                w = wsh[l15 * 432 + ic * 9 + kk];
            }
            wfrag[kb][j] = (short)f2bf(w);
        }
    }
    const float bv = (l15 < 9) ? bias[l15] : 0.f;
    __syncthreads();

    const float* itb = i_t + (size_t)b * 3 * (PLANE * 16);
    for (int v = tid; v < 3888; v += 256) {
        const int sp = v / 12;
        const int t  = v - sp * 12;
        const int c3 = t >> 2, fy = t & 3;
        const int ly = sp / 18, lx = sp - ly * 18;
        const int Y = Y0 - 1 + ly, X = X0 - 1 + lx;
        float4 val = make_float4(0.f, 0.f, 0.f, 0.f);
        if (Y >= 0 && Y < HSZ && X >= 0 && X < WSZ)
            val = *(const float4*)(itb + ((size_t)c3 * 1024 + (4 * Y + fy)) * 1024 + 4 * X);
        ushort4 u;
        u.x = f2bf(val.x); u.y = f2bf(val.y); u.z = f2bf(val.z); u.w = f2bf(val.w);
        *(ushort4*)(xs + sp * 56 + t * 4) = u;
    }
    __syncthreads();

    f32x4 acc0 = {0.f, 0.f, 0.f, 0.f}, acc1 = acc0, acc2 = acc0, acc3 = acc0;
#pragma unroll
    for (int kb = 0; kb < 14; ++kb) {
        const int k0 = kb * 32 + kg * 8;
        int off = 0;
        if (k0 < 432) {
            const int kk  = k0 / 48;
            const int ic0 = k0 - kk * 48;
            const int ky  = kk / 3;
            const int kx  = kk - 3 * ky;
            off = ((wv * 4 + ky) * 18 + l15 + kx) * 56 + ic0;
        }
        short8 a0 = *(const short8*)(xs + off);
        short8 a1 = *(const short8*)(xs + off + 1008);
        short8 a2 = *(const short8*)(xs + off + 2016);
        short8 a3 = *(const short8*)(xs + off + 3024);
        acc0 = __builtin_amdgcn_mfma_f32_16x16x32_bf16(a0, wfrag[kb], acc0, 0, 0, 0);
        acc1 = __builtin_amdgcn_mfma_f32_16x16x32_bf16(a1, wfrag[kb], acc1, 0, 0, 0);
        acc2 = __builtin_amdgcn_mfma_f32_16x16x32_bf16(a2, wfrag[kb], acc2, 0, 0, 0);
        acc3 = __builtin_amdgcn_mfma_f32_16x16x32_bf16(a3, wfrag[kb], acc3, 0, 0, 0);
    }

    if (l15 < 9) {
        float* fb = fbuf + (size_t)b * PLANE * 12;
#pragma unroll
        for (int i = 0; i < 4; ++i) {
            const int py = wv * 4 + i;
            f32x4 A = (i == 0) ? acc0 : (i == 1) ? acc1 : (i == 2) ? acc2 : acc3;
#pragma unroll
            for (int r = 0; r < 4; ++r) {
                const int px = kg * 4 + r;
                fb[((size_t)(Y0 + py) * WSZ + X0 + px) * 12 + l15] = fmaxf(A[r] + bv, 0.f);
            }
        }
    }
}

// ============================================================================
// Last-resort fallback (no usable ws): round-1 fused kernel.
// ============================================================================
__global__ __launch_bounds__(256, 2) void fused_dynfilter(
    const float* __restrict__ hbuf,
    const float* __restrict__ i_t,
    const float* __restrict__ wbuf,
    const float* __restrict__ bias,
    float* __restrict__ out)
{
    __shared__ __align__(16) float smem[15552];
    float4* xs4 = (float4*)smem;

    const int tid = threadIdx.x;
    const int px = tid & 15;
    const int py = tid >> 4;
    const int X0 = blockIdx.x * TILE;
    const int Y0 = blockIdx.y * TILE;
    const int b  = blockIdx.z;

    const float* itb = i_t + (size_t)b * 3 * 1024 * 1024;
    for (int v = tid; v < 3888; v += 256) {
        int sp = v / 12;
        int t  = v - sp * 12;
        int c3 = t >> 2, fy = t & 3;
        int ly = sp / 18, lx = sp - ly * 18;
        int Y = Y0 - 1 + ly, X = X0 - 1 + lx;
        float4 val = make_float4(0.f, 0.f, 0.f, 0.f);
        if (Y >= 0 && Y < HSZ && X >= 0 && X < WSZ)
            val = *(const float4*)(itb + ((size_t)c3 * 1024 + (4 * Y + fy)) * 1024 + 4 * X);
        xs4[t * 324 + sp] = val;
    }
    __syncthreads();

    float acc[9];
#pragma unroll
    for (int oc = 0; oc < 9; ++oc) acc[oc] = bias[oc];

#pragma unroll 1
    for (int ky = 0; ky < 3; ++ky)
#pragma unroll 1
        for (int kx = 0; kx < 3; ++kx) {
            const int sp = (py + ky) * 18 + (px + kx);
            const int kk = ky * 3 + kx;
#pragma unroll
            for (int ic4 = 0; ic4 < 12; ++ic4) {
                float4 v = xs4[ic4 * 324 + sp];
                const int chb = ((ic4 >> 2) << 4) + ((ic4 & 3) << 2);
                const float* wp = wbuf + (size_t)chb * 9 + kk;
                const float vv[4] = {v.x, v.y, v.z, v.w};
#pragma unroll
                for (int j = 0; j < 4; ++j)
#pragma unroll
                    for (int oc = 0; oc < 9; ++oc)
                        acc[oc] = fmaf(vv[j], wp[j * 9 + (size_t)oc * 432], acc[oc]);
            }
        }

    float flt[9];
#pragma unroll
    for (int oc = 0; oc < 9; ++oc) flt[oc] = fmaxf(acc[oc], 0.f);

    float4* hs4 = (float4*)smem;
#pragma unroll 1
    for (int cg = 0; cg < 16; ++cg) {
        __syncthreads();
        const float* hp = hbuf + ((size_t)b * NFC + cg * 4) * PLANE;
        for (int idx = tid; idx < 1296; idx += 256) {
            int c  = idx / 324;
            int sp = idx - c * 324;
            int ly = sp / 18, lx = sp - ly * 18;
            int Y = Y0 - 1 + ly, X = X0 - 1 + lx;
            float vv = 0.f;
            if (Y >= 0 && Y < HSZ && X >= 0 && X < WSZ)
                vv = hp[(size_t)c * PLANE + (size_t)Y * WSZ + X];
            smem[sp * 4 + c] = vv;
        }
        __syncthreads();

        float s0 = 0.f, s1 = 0.f, s2 = 0.f, s3 = 0.f;
#pragma unroll
        for (int ky = 0; ky < 3; ++ky)
#pragma unroll
            for (int kx = 0; kx < 3; ++kx) {
                float4 v = hs4[(py + ky) * 18 + (px + kx)];
                float f = flt[ky * 3 + kx];
                s0 = fmaf(v.x, f, s0);
                s1 = fmaf(v.y, f, s1);
                s2 = fmaf(v.z, f, s2);
                s3 = fmaf(v.w, f, s3);
            }
        size_t o = (((size_t)b * NFC + cg * 4) * HSZ + (Y0 + py)) * WSZ + (X0 + px);
        out[o]                     = s0;
        out[o + (size_t)PLANE]     = s1;
        out[o + (size_t)2 * PLANE] = s2;
        out[o + (size_t)3 * PLANE] = s3;
    }
}

extern "C" void kernel_launch(void* const* d_in, const int* in_sizes, int n_in,
                              void* d_out, int out_size, void* d_ws, size_t ws_size,
                              hipStream_t stream) {
    const float* h      = (const float*)d_in[0];
    const float* i_t    = (const float*)d_in[1];
    const float* conv_w = (const float*)d_in[2];
    const float* conv_b = (const float*)d_in[3];
    float* out = (float*)d_out;

    const int B = in_sizes[0] / (NFC * PLANE);
    const size_t fbuf_sz  = (size_t)B * PLANE * 12 * sizeof(float);
    const size_t wfrag_sz = 14 * 512 * sizeof(unsigned short);

    if (ws_size >= fbuf_sz + wfrag_sz) {
        float* fbuf = (float*)d_ws;
        unsigned short* wfragG = (unsigned short*)((char*)d_ws + fbuf_sz);
        prep_wfrag<<<dim3(14), 64, 0, stream>>>(conv_w, wfragG);
        dim3 g1(WSZ / 16, HSZ / 8, B);
        filter_conv_mfma2<<<g1, 128, 0, stream>>>(i_t, wfragG, conv_b, fbuf);
        dim3 g2((WSZ / 32) * 8, HSZ / TILE, B);
        dyn_apply4<<<g2, 256, 0, stream>>>(h, fbuf, out);
    } else if (ws_size >= fbuf_sz) {
        float* fbuf = (float*)d_ws;
        dim3 g1(WSZ / TILE, HSZ / TILE, B);
        filter_conv_mfma<<<g1, 256, 0, stream>>>(i_t, conv_w, conv_b, fbuf);
        dim3 g2((WSZ / 32) * 8, HSZ / TILE, B);
        dyn_apply4<<<g2, 256, 0, stream>>>(h, fbuf, out);
    } else {
        dim3 grid(WSZ / TILE, HSZ / TILE, B);
        fused_dynfilter<<<grid, 256, 0, stream>>>(h, i_t, conv_w, conv_b, out);
    }
}

// Round 6
// 125.744 us; speedup vs baseline: 1.5894x; 1.0952x over previous
//
#include <hip/hip_runtime.h>

#define TILE 16
#define HSZ 256
#define WSZ 256
#define NFC 64
#define PLANE (HSZ * WSZ)

typedef __attribute__((ext_vector_type(8))) short short8;
typedef __attribute__((ext_vector_type(4))) float f32x4;

__device__ inline unsigned short f2bf(float f) {
    unsigned u = __builtin_bit_cast(unsigned, f);
    return (unsigned short)((u + 0x7fffu + ((u >> 16) & 1u)) >> 16);   // RTNE
}

// ============================================================================
// Kernel 0: repack conv_w into MFMA B-fragment layout wfragG[kb][lane][8] bf16.
// K order: k = tap*48 + ic  (tap-major so every 8-k run = 8 contiguous chans).
// ============================================================================
__global__ void prep_wfrag(const float* __restrict__ wbuf,
                           unsigned short* __restrict__ wfragG)
{
    const int kb   = blockIdx.x;        // 0..13
    const int lane = threadIdx.x;       // 0..63
    const int l15  = lane & 15;         // oc
    const int kg   = lane >> 4;
    unsigned short v8[8];
#pragma unroll
    for (int j = 0; j < 8; ++j) {
        const int k = kb * 32 + kg * 8 + j;
        float w = 0.f;
        if (k < 432 && l15 < 9) {
            const int kk = k / 48;
            const int ic = k - kk * 48;
            w = wbuf[l15 * 432 + ic * 9 + kk];
        }
        v8[j] = f2bf(w);
    }
    unsigned short* p = wfragG + (size_t)kb * 512 + lane * 8;
    *(ushort4*)(p)     = ushort4{v8[0], v8[1], v8[2], v8[3]};
    *(ushort4*)(p + 4) = ushort4{v8[4], v8[5], v8[6], v8[7]};
}

// ============================================================================
// Kernel 1: filter prediction as MFMA implicit GEMM.
// Tile 16(x) x 8(y) px, 256 threads (4 waves; wave wv owns px rows 2wv,2wv+1).
// LDS: xs[sp = 10x18][48 ch] bf16. 9-round batched float4 staging.
// Output: 9 planes fbuf[oc][b][y][x] (coalesced write via LDS transpose).
// ============================================================================
__global__ __launch_bounds__(256) void filter_conv_mfma3(
    const float* __restrict__ i_t,
    const unsigned short* __restrict__ wfragG,
    const float* __restrict__ bias,
    float* __restrict__ fbuf, int Bn)
{
    __shared__ __align__(16) unsigned short xs[180 * 48];   // 17280 B

    const int tid  = threadIdx.x;
    const int X0 = blockIdx.x * 16;
    const int Y0 = blockIdx.y * 8;
    const int b  = blockIdx.z;
    const int lane = tid & 63;
    const int l15  = tid & 15;          // A: px col / B,C: oc
    const int kg   = (tid >> 4) & 3;    // k-subgroup
    const int wv   = tid >> 6;          // wave -> px rows 2wv, 2wv+1

    const float bv = (l15 < 9) ? bias[l15] : 0.f;
    const float* itb = i_t + (size_t)b * 3 * (PLANE * 16);

    // ---- stage guidance tile: 2160 float4 jobs, 9 rounds, loads batched first
    {
        float4 lreg[9]; int sdst[9];
#pragma unroll
        for (int k = 0; k < 9; ++k) {
            const int v = tid + 256 * k;
            const int sp = v / 12, t = v - sp * 12;     // t = c3*4+fy
            const int c3 = t >> 2, fy = t & 3;
            const int ly = sp / 18, lx = sp - ly * 18;
            const int Y = Y0 - 1 + ly, X = X0 - 1 + lx;
            float4 val = make_float4(0.f, 0.f, 0.f, 0.f);
            if (v < 2160 && (unsigned)Y < HSZ && (unsigned)X < WSZ)
                val = *(const float4*)(itb + ((size_t)c3 * 1024 + (4 * Y + fy)) * 1024 + 4 * X);
            lreg[k] = val;
            sdst[k] = (v < 2160) ? (sp * 48 + t * 4) : -1;
        }
#pragma unroll
        for (int k = 0; k < 9; ++k) {
            if (sdst[k] >= 0) {
                ushort4 u{f2bf(lreg[k].x), f2bf(lreg[k].y), f2bf(lreg[k].z), f2bf(lreg[k].w)};
                *(ushort4*)(xs + sdst[k]) = u;
            }
        }
    }

    // ---- B-fragments: 14 coalesced dwordx4 from wfragG (L2-hot)
    short8 wf[14];
#pragma unroll
    for (int kb = 0; kb < 14; ++kb)
        wf[kb] = *(const short8*)(wfragG + (size_t)kb * 512 + lane * 8);

    __syncthreads();

    // ---- 14 K-blocks x 2 row-tiles of MFMA per wave
    f32x4 acc0 = {0.f, 0.f, 0.f, 0.f}, acc1 = acc0;
#pragma unroll
    for (int kb = 0; kb < 14; ++kb) {
        const int k0 = kb * 32 + kg * 8;
        int off = 0;
        if (k0 < 432) {
            const int kk  = k0 / 48;
            const int ic0 = k0 - kk * 48;
            const int ky  = kk / 3;
            const int kx  = kk - 3 * ky;
            off = ((2 * wv + ky) * 18 + l15 + kx) * 48 + ic0;   // 16B-aligned
        }
        short8 a0 = *(const short8*)(xs + off);
        short8 a1 = *(const short8*)(xs + off + 864);    // +1 px row (18*48)
        acc0 = __builtin_amdgcn_mfma_f32_16x16x32_bf16(a0, wf[kb], acc0, 0, 0, 0);
        acc1 = __builtin_amdgcn_mfma_f32_16x16x32_bf16(a1, wf[kb], acc1, 0, 0, 0);
    }

    // ---- epilogue: lf[oc][py][px] in LDS -> coalesced plane stores
    __syncthreads();
    float* lf = (float*)xs;                    // 9*8*16 = 1152 floats
    if (l15 < 9) {
#pragma unroll
        for (int t = 0; t < 2; ++t) {
            const int py = 2 * wv + t;
            f32x4 A = t ? acc1 : acc0;
#pragma unroll
            for (int r = 0; r < 4; ++r) {
                const int px = kg * 4 + r;
                lf[l15 * 128 + py * 16 + px] = fmaxf(A[r] + bv, 0.f);
            }
        }
    }
    __syncthreads();
    // 288 float4 jobs: oc = v>>5, py = (v&31)>>2, xf4 = v&3
    {
        const int v0 = tid;
        const int oc = v0 >> 5, rem = v0 & 31, py = rem >> 2, xf4 = rem & 3;
        *(float4*)(fbuf + ((size_t)oc * Bn + b) * PLANE + (size_t)(Y0 + py) * WSZ + X0 + xf4 * 4)
            = *(const float4*)(lf + oc * 128 + py * 16 + xf4 * 4);
        if (tid < 32) {
            const int v1 = tid + 256;
            const int oc1 = v1 >> 5, rem1 = v1 & 31, py1 = rem1 >> 2, xf41 = rem1 & 3;
            *(float4*)(fbuf + ((size_t)oc1 * Bn + b) * PLANE + (size_t)(Y0 + py1) * WSZ + X0 + xf41 * 4)
                = *(const float4*)(lf + oc1 * 128 + py1 * 16 + xf41 * 4);
        }
    }
}

// ============================================================================
// Kernel 2: apply per-pixel filters to h.
// Block = 32x16 px x 8 ch (2048 blocks); thread = 4 px x 4 ch.
// LDS: hs[8 ch][18 rows][40 cols] floats; data cols 0..39 = h cols X0-4..X0+35.
// Staging: 6-round float4 batch (all loads in flight before ds_writes).
// Filters read as 9 coalesced float4 loads from the plane layout.
// ============================================================================
__global__ __launch_bounds__(256, 4) void dyn_apply5(
    const float* __restrict__ hbuf,
    const float* __restrict__ fbuf,
    float* __restrict__ out, int Bn)
{
    __shared__ __align__(16) float hs[8 * 720];   // 23040 B

    const int tid  = threadIdx.x;
    const int pq   = tid & 7;                 // px group of 4 (x = X0+pq*4..+3)
    const int py   = (tid >> 3) & 15;
    const int c_lo = tid >> 7;                // 0..1
    const int cg = blockIdx.x & 7;
    const int X0 = (blockIdx.x >> 3) * 32;
    const int Y0 = blockIdx.y * TILE;
    const int b  = blockIdx.z;

    // per-pixel filters: 9 coalesced float4 loads (flt4[oc][j] = tap oc, px j)
    float4 flt4[9];
    {
        const size_t pix = (size_t)b * PLANE + (size_t)(Y0 + py) * WSZ + X0 + pq * 4;
#pragma unroll
        for (int oc = 0; oc < 9; ++oc)
            flt4[oc] = *(const float4*)(fbuf + (size_t)oc * Bn * PLANE + pix);
    }

    // stage 8 channel planes: 8*18*10 = 1440 float4 jobs, 6 rounds
    const float* hp = hbuf + ((size_t)b * NFC + cg * 8) * PLANE;
    {
        float4 rv[6]; int dst[6];
#pragma unroll
        for (int k = 0; k < 6; ++k) {
            const int v = tid + 256 * k;
            const int c = v / 180;
            const int r = v - c * 180;
            const int row = r / 10, xq = r - row * 10;
            const int Y  = Y0 - 1 + row;
            const int X4 = X0 - 4 + xq * 4;
            float4 val = make_float4(0.f, 0.f, 0.f, 0.f);
            if (v < 1440 && (unsigned)Y < HSZ && (unsigned)X4 < WSZ)
                val = *(const float4*)(hp + (size_t)c * PLANE + (size_t)Y * WSZ + X4);
            rv[k] = val;
            dst[k] = (v < 1440) ? (c * 720 + row * 40 + xq * 4) : -1;
        }
#pragma unroll
        for (int k = 0; k < 6; ++k)
            if (dst[k] >= 0) *(float4*)(hs + dst[k]) = rv[k];
    }
    __syncthreads();

    float a[4][4];
#pragma unroll
    for (int cc = 0; cc < 4; ++cc)
#pragma unroll
        for (int j = 0; j < 4; ++j) a[cc][j] = 0.f;

#pragma unroll
    for (int cc = 0; cc < 4; ++cc) {
        const float* pl = hs + (c_lo + 2 * cc) * 720;
#pragma unroll
        for (int ky = 0; ky < 3; ++ky) {
            const float* rp = pl + (py + ky) * 40 + pq * 4;   // col 0 = X0-4
            float4 w0 = *(const float4*)rp;
            float4 w1 = *(const float4*)(rp + 4);
            float  w8 = rp[8];
            const float vs[9] = {w0.x, w0.y, w0.z, w0.w, w1.x, w1.y, w1.z, w1.w, w8};
#pragma unroll
            for (int kx = 0; kx < 3; ++kx)
#pragma unroll
                for (int j = 0; j < 4; ++j)
                    a[cc][j] = fmaf(vs[3 + kx + j], flt4[ky * 3 + kx][j], a[cc][j]);
        }
    }

#pragma unroll
    for (int cc = 0; cc < 4; ++cc) {
        const int ch = cg * 8 + c_lo + 2 * cc;
        *(float4*)(out + ((size_t)b * NFC + ch) * PLANE
                       + (size_t)(Y0 + py) * WSZ + X0 + pq * 4)
            = make_float4(a[cc][0], a[cc][1], a[cc][2], a[cc][3]);
    }
}

// ============================================================================
// Last-resort fallback (no usable ws): round-1 fused kernel.
// ============================================================================
__global__ __launch_bounds__(256, 2) void fused_dynfilter(
    const float* __restrict__ hbuf,
    const float* __restrict__ i_t,
    const float* __restrict__ wbuf,
    const float* __restrict__ bias,
    float* __restrict__ out)
{
    __shared__ __align__(16) float smem[15552];
    float4* xs4 = (float4*)smem;

    const int tid = threadIdx.x;
    const int px = tid & 15;
    const int py = tid >> 4;
    const int X0 = blockIdx.x * TILE;
    const int Y0 = blockIdx.y * TILE;
    const int b  = blockIdx.z;

    const float* itb = i_t + (size_t)b * 3 * 1024 * 1024;
    for (int v = tid; v < 3888; v += 256) {
        int sp = v / 12;
        int t  = v - sp * 12;
        int c3 = t >> 2, fy = t & 3;
        int ly = sp / 18, lx = sp - ly * 18;
        int Y = Y0 - 1 + ly, X = X0 - 1 + lx;
        float4 val = make_float4(0.f, 0.f, 0.f, 0.f);
        if (Y >= 0 && Y < HSZ && X >= 0 && X < WSZ)
            val = *(const float4*)(itb + ((size_t)c3 * 1024 + (4 * Y + fy)) * 1024 + 4 * X);
        xs4[t * 324 + sp] = val;
    }
    __syncthreads();

    float acc[9];
#pragma unroll
    for (int oc = 0; oc < 9; ++oc) acc[oc] = bias[oc];

#pragma unroll 1
    for (int ky = 0; ky < 3; ++ky)
#pragma unroll 1
        for (int kx = 0; kx < 3; ++kx) {
            const int sp = (py + ky) * 18 + (px + kx);
            const int kk = ky * 3 + kx;
#pragma unroll
            for (int ic4 = 0; ic4 < 12; ++ic4) {
                float4 v = xs4[ic4 * 324 + sp];
                const int chb = ((ic4 >> 2) << 4) + ((ic4 & 3) << 2);
                const float* wp = wbuf + (size_t)chb * 9 + kk;
                const float vv[4] = {v.x, v.y, v.z, v.w};
#pragma unroll
                for (int j = 0; j < 4; ++j)
#pragma unroll
                    for (int oc = 0; oc < 9; ++oc)
                        acc[oc] = fmaf(vv[j], wp[j * 9 + (size_t)oc * 432], acc[oc]);
            }
        }

    float flt[9];
#pragma unroll
    for (int oc = 0; oc < 9; ++oc) flt[oc] = fmaxf(acc[oc], 0.f);

    float4* hs4 = (float4*)smem;
#pragma unroll 1
    for (int cg = 0; cg < 16; ++cg) {
        __syncthreads();
        const float* hp = hbuf + ((size_t)b * NFC + cg * 4) * PLANE;
        for (int idx = tid; idx < 1296; idx += 256) {
            int c  = idx / 324;
            int sp = idx - c * 324;
            int ly = sp / 18, lx = sp - ly * 18;
            int Y = Y0 - 1 + ly, X = X0 - 1 + lx;
            float vv = 0.f;
            if (Y >= 0 && Y < HSZ && X >= 0 && X < WSZ)
                vv = hp[(size_t)c * PLANE + (size_t)Y * WSZ + X];
            smem[sp * 4 + c] = vv;
        }
        __syncthreads();

        float s0 = 0.f, s1 = 0.f, s2 = 0.f, s3 = 0.f;
#pragma unroll
        for (int ky = 0; ky < 3; ++ky)
#pragma unroll
            for (int kx = 0; kx < 3; ++kx) {
                float4 v = hs4[(py + ky) * 18 + (px + kx)];
                float f = flt[ky * 3 + kx];
                s0 = fmaf(v.x, f, s0);
                s1 = fmaf(v.y, f, s1);
                s2 = fmaf(v.z, f, s2);
                s3 = fmaf(v.w, f, s3);
            }
        size_t o = (((size_t)b * NFC + cg * 4) * HSZ + (Y0 + py)) * WSZ + (X0 + px);
        out[o]                     = s0;
        out[o + (size_t)PLANE]     = s1;
        out[o + (size_t)2 * PLANE] = s2;
        out[o + (size_t)3 * PLANE] = s3;
    }
}

extern "C" void kernel_launch(void* const* d_in, const int* in_sizes, int n_in,
                              void* d_out, int out_size, void* d_ws, size_t ws_size,
                              hipStream_t stream) {
    const float* h      = (const float*)d_in[0];
    const float* i_t    = (const float*)d_in[1];
    const float* conv_w = (const float*)d_in[2];
    const float* conv_b = (const float*)d_in[3];
    float* out = (float*)d_out;

    const int B = in_sizes[0] / (NFC * PLANE);
    const size_t fbuf_sz  = (size_t)9 * B * PLANE * sizeof(float);
    const size_t wfrag_sz = 14 * 512 * sizeof(unsigned short);

    if (ws_size >= fbuf_sz + wfrag_sz) {
        float* fbuf = (float*)d_ws;
        unsigned short* wfragG = (unsigned short*)((char*)d_ws + fbuf_sz);
        prep_wfrag<<<dim3(14), 64, 0, stream>>>(conv_w, wfragG);
        dim3 g1(WSZ / 16, HSZ / 8, B);
        filter_conv_mfma3<<<g1, 256, 0, stream>>>(i_t, wfragG, conv_b, fbuf, B);
        dim3 g2((WSZ / 32) * 8, HSZ / TILE, B);
        dyn_apply5<<<g2, 256, 0, stream>>>(h, fbuf, out, B);
    } else {
        dim3 grid(WSZ / TILE, HSZ / TILE, B);
        fused_dynfilter<<<grid, 256, 0, stream>>>(h, i_t, conv_w, conv_b, out);
    }
}